// Round 10
// baseline (1492.240 us; speedup 1.0000x reference)
//
#include <hip/hip_runtime.h>

// GRU: B=256, T=2048, I=2, H=128. One workgroup (512 thr = 8 waves) per batch.
// R10 = R6's 16-col-slice mapping + R9's proven techniques.
//   Rationale: wave64 ds_read_b128 costs ~8 cyc of LDS *return bandwidth*
//   (1 KB/instr at 128 B/cyc) regardless of broadcast; R9 pays 64/step
//   (~512 cyc LDS pipe). 16-col slices halve per-lane LDS bytes -> 32/step.
//   R6 tested this mapping but drowned it under 18 VOLATILE asm fences; here
//   the butterfly is non-volatile single-instruction v_add_f32_dpp (R9).
// Mapping (R6-proven, absmax 0): r16=tid&15, q=(r16&3)|((r16>>1)&4) in 0..7
//   (16-col slice), jp=((tid>>4)<<1)|((r16>>2)&1) in 0..63 (row pair).
//   Thread owns rows {g*128 + 2jp + p : g=r,z,n; p=0,1} x cols [16q,16q+16).
//   Reduce group = 8 lanes same (jp): quad_perm xor1, xor2, row_ror:8.
// Critical-path folds: r/z input projections and n's b_hh are pre-folded
//   into accumulator init (x1/8: butterfly sums 8 replicas); weights
//   prescaled by -log2e (r/z) and 2log2e (n) so gates are raw exp2+rcp.
// Consumers: lanes q<2 handle p=q (hi=2jp+q). One barrier/step.

#define BB 256
#define TT 2048
#define HH 128
#define NT 512
#define SLW 20              // words per 16-float h slice (+4 pad)
#define HWORDS (8 * SLW)    // 160

typedef float v4f __attribute__((ext_vector_type(4)));
typedef float v2f __attribute__((ext_vector_type(2)));

#define LO2(v) __builtin_shufflevector((v), (v), 0, 1)
#define HI2(v) __builtin_shufflevector((v), (v), 2, 3)

// x += dpp(x) in one v_add_f32_dpp; s_nop 1 covers the VALU->DPP hazard.
// NON-volatile: schedulable into the surrounding FMA stream.
#define DPP_ADD(x, CTRLSTR) do { float _d;                                   \
    asm("s_nop 1\n\t"                                                        \
        "v_add_f32_dpp %0, %1, %1 " CTRLSTR " row_mask:0xf bank_mask:0xf"    \
        : "=v"(_d) : "v"(x));                                                \
    (x) = _d; } while (0)

__global__ __launch_bounds__(NT, 2) void gru_seq_kernel(
    const float* __restrict__ x,        // [B, T, 2]
    const int*   __restrict__ lengths,  // [B]
    const float* __restrict__ W_ih,     // [384, 2]
    const float* __restrict__ W_hh,     // [384, 128]
    const float* __restrict__ b_ih,     // [384]
    const float* __restrict__ b_hh,     // [384]
    const float* __restrict__ head_w,   // [128]
    const float* __restrict__ head_b,   // [1]
    float* __restrict__ out)            // [B]
{
    __shared__ __align__(16) float x_lds[(TT + 1) * 2];  // +1: safe prefetch
    __shared__ __align__(16) float h_lds[2][HWORDS];
    __shared__ float red[HH];

    const int tid = threadIdx.x;
    const int r16 = tid & 15;
    const int q   = (r16 & 3) | ((r16 >> 1) & 4);            // col slice 0..7
    const int jp  = ((tid >> 4) << 1) | ((r16 >> 2) & 1);    // row pair 0..63
    const int b   = blockIdx.x;
    const int len = lengths[b];

    const float S_RZ = -1.4426950408889634f;   // -log2(e)
    const float S_N  =  2.8853900817779268f;   //  2*log2(e)

    // --- weights: rows {g,p} x 16-col slice q, prescaled (24 v4f) ---
    v4f wv[6][4];
    #pragma unroll
    for (int g = 0; g < 3; ++g) {
        const float s = (g == 2) ? S_N : S_RZ;
        #pragma unroll
        for (int p = 0; p < 2; ++p) {
            const v4f* Wp = (const v4f*)(W_hh + (size_t)(g * HH + 2 * jp + p) * HH + 16 * q);
            #pragma unroll
            for (int c = 0; c < 4; ++c) wv[g * 2 + p][c] = Wp[c] * s;
        }
    }

    // --- all-lane init constants (x 1/8: butterfly sums 8 replicas) ---
    float2 wiR[2], wiZ[2];
    float bR[2], bZ[2], bhN8[2];
    #pragma unroll
    for (int p = 0; p < 2; ++p) {
        const int hi = 2 * jp + p;
        const float s8 = S_RZ * 0.125f;
        float2 t;
        t = ((const float2*)W_ih)[hi];
        wiR[p] = make_float2(t.x * s8, t.y * s8);
        bR[p]  = (b_ih[hi] + b_hh[hi]) * s8;
        t = ((const float2*)W_ih)[HH + hi];
        wiZ[p] = make_float2(t.x * s8, t.y * s8);
        bZ[p]  = (b_ih[HH + hi] + b_hh[HH + hi]) * s8;
        bhN8[p] = b_hh[2 * HH + hi] * (S_N * 0.125f);
    }

    // --- consumer (q<2) constants for hidden unit hi = 2jp + q ---
    float winx = 0.f, winy = 0.f, bn = 0.f, hw = 0.f;
    const int hi = 2 * jp + q;
    if (q < 2) {
        const float2 t = ((const float2*)W_ih)[2 * HH + hi];
        winx = S_N * t.x; winy = S_N * t.y;
        bn   = S_N * b_ih[2 * HH + hi];
        hw   = head_w[hi];
    }

    // --- stage x[b] into LDS; zero both h buffers ---
    {
        const float4* xb4 = (const float4*)(x + (size_t)b * TT * 2);
        float4* xl4 = (float4*)x_lds;
        #pragma unroll
        for (int i = tid; i < TT * 2 / 4; i += NT) xl4[i] = xb4[i];
    }
    if (tid == 0) { x_lds[TT * 2] = 0.f; x_lds[TT * 2 + 1] = 0.f; }
    for (int i = tid; i < 2 * HWORDS; i += NT) ((float*)h_lds)[i] = 0.f;

    __syncthreads();

    float hreg = 0.0f;   // h[hi] held by q<2 lanes
    int buf = 0;
    const float2* x2 = (const float2*)x_lds;
    float2 xt = x2[0];

    for (int t = 0; t < len; ++t) {
        // h slice q: 4 x ds_read_b128 (20q+4i: all 32 banks exactly once)
        const v4f* hb = (const v4f*)&h_lds[buf][SLW * q];
        const v4f hv0 = hb[0], hv1 = hb[1], hv2 = hb[2], hv3 = hb[3];

        const float2 xt_next = x2[t + 1];   // prefetch

        // per-step accumulator inits (xp/8 for r/z; bhn/8 for n)
        v2f aA[6], aB[6];
        #pragma unroll
        for (int rr = 0; rr < 6; ++rr) { aA[rr] = (v2f){0.f, 0.f}; aB[rr] = (v2f){0.f, 0.f}; }
        aA[0].x = fmaf(wiR[0].x, xt.x, fmaf(wiR[0].y, xt.y, bR[0]));
        aA[1].x = fmaf(wiR[1].x, xt.x, fmaf(wiR[1].y, xt.y, bR[1]));
        aA[2].x = fmaf(wiZ[0].x, xt.x, fmaf(wiZ[0].y, xt.y, bZ[0]));
        aA[3].x = fmaf(wiZ[1].x, xt.x, fmaf(wiZ[1].y, xt.y, bZ[1]));
        aA[4].x = bhN8[0];
        aA[5].x = bhN8[1];

        const v2f h0l = LO2(hv0), h0h = HI2(hv0), h1l = LO2(hv1), h1h = HI2(hv1);
        const v2f h2l = LO2(hv2), h2h = HI2(hv2), h3l = LO2(hv3), h3h = HI2(hv3);

        float acc[6];
        #pragma unroll
        for (int rr = 0; rr < 6; ++rr) {
            v2f a = aA[rr], c = aB[rr];
            a = __builtin_elementwise_fma(LO2(wv[rr][0]), h0l, a);
            c = __builtin_elementwise_fma(HI2(wv[rr][0]), h0h, c);
            a = __builtin_elementwise_fma(LO2(wv[rr][1]), h1l, a);
            c = __builtin_elementwise_fma(HI2(wv[rr][1]), h1h, c);
            a = __builtin_elementwise_fma(LO2(wv[rr][2]), h2l, a);
            c = __builtin_elementwise_fma(HI2(wv[rr][2]), h2h, c);
            a = __builtin_elementwise_fma(LO2(wv[rr][3]), h3l, a);
            c = __builtin_elementwise_fma(HI2(wv[rr][3]), h3h, c);
            acc[rr] = (a.x + a.y) + (c.x + c.y);
        }

        // 8-lane butterfly (group = same jp): acc-major interleave
        DPP_ADD(acc[0], "quad_perm:[1,0,3,2]");
        DPP_ADD(acc[1], "quad_perm:[1,0,3,2]");
        DPP_ADD(acc[2], "quad_perm:[1,0,3,2]");
        DPP_ADD(acc[3], "quad_perm:[1,0,3,2]");
        DPP_ADD(acc[4], "quad_perm:[1,0,3,2]");
        DPP_ADD(acc[5], "quad_perm:[1,0,3,2]");
        DPP_ADD(acc[0], "quad_perm:[2,3,0,1]");
        DPP_ADD(acc[1], "quad_perm:[2,3,0,1]");
        DPP_ADD(acc[2], "quad_perm:[2,3,0,1]");
        DPP_ADD(acc[3], "quad_perm:[2,3,0,1]");
        DPP_ADD(acc[4], "quad_perm:[2,3,0,1]");
        DPP_ADD(acc[5], "quad_perm:[2,3,0,1]");
        DPP_ADD(acc[0], "row_ror:8");
        DPP_ADD(acc[1], "row_ror:8");
        DPP_ADD(acc[2], "row_ror:8");
        DPP_ADD(acc[3], "row_ror:8");
        DPP_ADD(acc[4], "row_ror:8");
        DPP_ADD(acc[5], "row_ror:8");

        if (q < 2) {
            // acc already contains scaled (dot + xp + biases)
            const float r = __builtin_amdgcn_rcpf(1.f + __builtin_amdgcn_exp2f(acc[q]));
            const float z = __builtin_amdgcn_rcpf(1.f + __builtin_amdgcn_exp2f(acc[2 + q]));
            const float xn = fmaf(winx, xt.x, fmaf(winy, xt.y, bn));
            const float u = __builtin_amdgcn_exp2f(fmaf(r, acc[4 + q], xn));
            const float n = fmaf(-2.f, __builtin_amdgcn_rcpf(1.f + u), 1.f);
            hreg = n + z * (hreg - n);
            h_lds[buf ^ 1][SLW * (hi >> 4) + (hi & 15)] = hreg;
        }
        __syncthreads();
        buf ^= 1;
        xt = xt_next;
    }

    // --- head: out[b] = dot(h, head_w) + head_b ---
    if (q < 2) red[hi] = hreg * hw;
    __syncthreads();
    if (tid < 64) {
        float v = red[tid] + red[tid + 64];
        #pragma unroll
        for (int off = 32; off > 0; off >>= 1) v += __shfl_xor(v, off, 64);
        if (tid == 0) out[b] = v + head_b[0];
    }
}

extern "C" void kernel_launch(void* const* d_in, const int* in_sizes, int n_in,
                              void* d_out, int out_size, void* d_ws, size_t ws_size,
                              hipStream_t stream) {
    const float* x      = (const float*)d_in[0];
    const int*   len    = (const int*)  d_in[1];
    const float* W_ih   = (const float*)d_in[2];
    const float* W_hh   = (const float*)d_in[3];
    const float* b_ih   = (const float*)d_in[4];
    const float* b_hh   = (const float*)d_in[5];
    const float* head_w = (const float*)d_in[6];
    const float* head_b = (const float*)d_in[7];
    float* out = (float*)d_out;

    gru_seq_kernel<<<BB, NT, 0, stream>>>(x, len, W_ih, W_hh, b_ih, b_hh,
                                          head_w, head_b, out);
}

// Round 11
// 999.504 us; speedup vs baseline: 1.4930x; 1.4930x over previous
//
#include <hip/hip_runtime.h>

// GRU: B=256, T=2048, I=2, H=128. One workgroup (512 thr = 8 waves) per batch.
// R11 = R9 (best: 1069 us) + serial-tail shavings. R9 structure frozen:
//   thread (q=tid&3, j=tid>>2) owns q-th 32-col slice of gate rows
//   {j, 128+j, 256+j}; h double-buffered in LDS (40-word slice stride,
//   conflict-free quad-broadcast reads); packed v_pk_fma_f32 dots; 2-stage
//   quad butterfly via non-volatile single-instruction v_add_f32_dpp;
//   exp2/rcp gates with prescaled weights; x[t+1] prefetch; 1 barrier/step.
// R11 deltas:
//  (1) xp (r/z) and bhn (n) folded into accumulator init, scaled 1/4 (quad
//      butterfly sums 4 replicas) -> butterfly output feeds exp2 directly;
//      removes 3 serial adds from the phase-locked tail.
//  (2) gate ALU unmasked (all quad lanes hold identical sums post-butterfly;
//      only ds_write/h_reg update masked) -> no exec churn, schedulable.
//  (3) per-gate accumulator combine via one v_pk_add_f32 + one add.
// NOTE (R4/R6/R10, 3x falsified): 16-col-slice/8-lane-reduce family always
// regresses ~+500..950 cyc/step regardless of reduce implementation. Do not
// revisit. LDS-read halving does not pay at this operating point.

#define BB 256
#define TT 2048
#define HH 128
#define NT 512
#define HWORDS 160   // 4 slices x 40 words (32 data + 8 pad)

typedef float v4f __attribute__((ext_vector_type(4)));
typedef float v2f __attribute__((ext_vector_type(2)));

#define LO2(v) __builtin_shufflevector((v), (v), 0, 1)
#define HI2(v) __builtin_shufflevector((v), (v), 2, 3)

// x += dpp(x) in one v_add_f32_dpp; s_nop 1 covers the VALU->DPP hazard.
// Non-volatile: schedulable.
#define DPP_ADD_Q(x, QPSTR) do { float _d;                                   \
    asm("s_nop 1\n\t"                                                        \
        "v_add_f32_dpp %0, %1, %1 " QPSTR " row_mask:0xf bank_mask:0xf"      \
        : "=v"(_d) : "v"(x));                                                \
    (x) = _d; } while (0)

__global__ __launch_bounds__(NT, 2) void gru_seq_kernel(
    const float* __restrict__ x,        // [B, T, 2]
    const int*   __restrict__ lengths,  // [B]
    const float* __restrict__ W_ih,     // [384, 2]
    const float* __restrict__ W_hh,     // [384, 128]
    const float* __restrict__ b_ih,     // [384]
    const float* __restrict__ b_hh,     // [384]
    const float* __restrict__ head_w,   // [128]
    const float* __restrict__ head_b,   // [1]
    float* __restrict__ out)            // [B]
{
    __shared__ __align__(16) float x_lds[(TT + 1) * 2];  // +1: safe prefetch
    __shared__ __align__(16) float h_lds[2][HWORDS];
    __shared__ float red[8];

    const int tid = threadIdx.x;
    const int q = tid & 3;          // 32-col slice
    const int j = tid >> 2;         // hidden index 0..127
    const int b = blockIdx.x;
    const int len = lengths[b];

    const float S_RZ = -1.4426950408889634f;   // -log2(e)
    const float S_N  =  2.8853900817779268f;   //  2*log2(e)

    // --- weights for this thread's 3 row-slices, PRESCALED at load ---
    v4f wr[8], wz[8], wn[8];
    {
        const v4f* Wr = (const v4f*)(W_hh + (size_t)j * HH + q * 32);
        const v4f* Wz = (const v4f*)(W_hh + (size_t)(HH + j) * HH + q * 32);
        const v4f* Wn = (const v4f*)(W_hh + (size_t)(2 * HH + j) * HH + q * 32);
        #pragma unroll
        for (int i = 0; i < 8; ++i) {
            wr[i] = Wr[i] * S_RZ;
            wz[i] = Wz[i] * S_RZ;
            wn[i] = Wn[i] * S_N;
        }
    }

    // --- ALL-lane init constants (x 1/4: quad butterfly sums 4 replicas) ---
    // r/z: init = (W_ih.x + b_ih + b_hh) * S_RZ / 4    (per-step fmaf)
    // n:   init = b_hh * S_N / 4; xn stays on the consumer side.
    float wir0, wir1, br4, wiz0, wiz1, bz4, bhn4;
    {
        const float s4 = S_RZ * 0.25f;
        wir0 = s4 * W_ih[j * 2];        wir1 = s4 * W_ih[j * 2 + 1];
        br4  = s4 * (b_ih[j] + b_hh[j]);
        wiz0 = s4 * W_ih[(HH + j) * 2]; wiz1 = s4 * W_ih[(HH + j) * 2 + 1];
        bz4  = s4 * (b_ih[HH + j] + b_hh[HH + j]);
        bhn4 = (S_N * 0.25f) * b_hh[2 * HH + j];
    }
    // consumer-side n-gate input proj + head weight (valid on all lanes)
    float win0, win1, bn, hw;
    {
        win0 = S_N * W_ih[(2 * HH + j) * 2];
        win1 = S_N * W_ih[(2 * HH + j) * 2 + 1];
        bn   = S_N * b_ih[2 * HH + j];
        hw   = head_w[j];
    }

    // --- stage x[b] into LDS (float4, coalesced) ---
    {
        const float4* xb4 = (const float4*)(x + (size_t)b * TT * 2);
        float4* xl4 = (float4*)x_lds;
        #pragma unroll
        for (int i = tid; i < TT * 2 / 4; i += NT) xl4[i] = xb4[i];
    }
    if (tid == 0) { x_lds[TT * 2] = 0.f; x_lds[TT * 2 + 1] = 0.f; }
    // zero both h buffers
    for (int i = tid; i < 2 * HWORDS; i += NT) ((float*)h_lds)[i] = 0.f;

    __syncthreads();

    float h_reg = 0.0f;   // h[j]; only q==0 lanes' value is live
    int buf = 0;
    const float2* x2 = (const float2*)x_lds;
    float2 xt = x2[0];

    for (int t = 0; t < len; ++t) {
        // h slice reads (broadcast within quad, banks disjoint across q)
        const v4f* hb = (const v4f*)&h_lds[buf][40 * q];
        v4f hv[8];
        #pragma unroll
        for (int i = 0; i < 8; ++i) hv[i] = hb[i];

        const float2 xt_next = x2[t + 1];   // prefetch

        // accumulator init: xp/4 (r,z) and bhn/4 (n) pre-folded
        v2f arA = {fmaf(wir0, xt.x, fmaf(wir1, xt.y, br4)), 0.f};
        v2f azA = {fmaf(wiz0, xt.x, fmaf(wiz1, xt.y, bz4)), 0.f};
        v2f anA = {bhn4, 0.f};
        v2f arB = {0.f, 0.f}, azB = {0.f, 0.f}, anB = {0.f, 0.f};
        #pragma unroll
        for (int i = 0; i < 8; ++i) {
            const v2f hl = LO2(hv[i]), hh = HI2(hv[i]);
            arA = __builtin_elementwise_fma(LO2(wr[i]), hl, arA);
            arB = __builtin_elementwise_fma(HI2(wr[i]), hh, arB);
            azA = __builtin_elementwise_fma(LO2(wz[i]), hl, azA);
            azB = __builtin_elementwise_fma(HI2(wz[i]), hh, azB);
            anA = __builtin_elementwise_fma(LO2(wn[i]), hl, anA);
            anB = __builtin_elementwise_fma(HI2(wn[i]), hh, anB);
        }
        // packed combine: one v_pk_add_f32 + one scalar add per gate
        const v2f arS = arA + arB, azS = azA + azB, anS = anA + anB;
        float ar = arS.x + arS.y;
        float az = azS.x + azS.y;
        float an = anS.x + anS.y;

        // quad butterfly, acc-major interleave (non-volatile, schedulable)
        DPP_ADD_Q(ar, "quad_perm:[1,0,3,2]");
        DPP_ADD_Q(az, "quad_perm:[1,0,3,2]");
        DPP_ADD_Q(an, "quad_perm:[1,0,3,2]");
        DPP_ADD_Q(ar, "quad_perm:[2,3,0,1]");
        DPP_ADD_Q(az, "quad_perm:[2,3,0,1]");
        DPP_ADD_Q(an, "quad_perm:[2,3,0,1]");

        // gate chain UNMASKED (all quad lanes hold identical full sums);
        // ar/az/an already include xp and biases (prescaled)
        const float r = __builtin_amdgcn_rcpf(1.f + __builtin_amdgcn_exp2f(ar));
        const float z = __builtin_amdgcn_rcpf(1.f + __builtin_amdgcn_exp2f(az));
        const float xn = fmaf(win0, xt.x, fmaf(win1, xt.y, bn));
        const float u = __builtin_amdgcn_exp2f(fmaf(r, an, xn));
        const float n = fmaf(-2.f, __builtin_amdgcn_rcpf(1.f + u), 1.f);
        const float h_new = n + z * (h_reg - n);
        if (q == 0) {
            h_reg = h_new;
            h_lds[buf ^ 1][40 * (j >> 5) + (j & 31)] = h_new;
        }
        __syncthreads();
        buf ^= 1;
        xt = xt_next;
    }

    // --- head: out[b] = dot(h, head_w) + head_b ---
    float p = (q == 0) ? h_reg * hw : 0.0f;
    #pragma unroll
    for (int off = 32; off > 0; off >>= 1) p += __shfl_xor(p, off);
    const int wid = tid >> 6;
    if ((tid & 63) == 0) red[wid] = p;
    __syncthreads();
    if (tid == 0) {
        float s = red[0];
        #pragma unroll
        for (int i = 1; i < 8; ++i) s += red[i];
        out[b] = s + head_b[0];
    }
}

extern "C" void kernel_launch(void* const* d_in, const int* in_sizes, int n_in,
                              void* d_out, int out_size, void* d_ws, size_t ws_size,
                              hipStream_t stream) {
    const float* x      = (const float*)d_in[0];
    const int*   len    = (const int*)  d_in[1];
    const float* W_ih   = (const float*)d_in[2];
    const float* W_hh   = (const float*)d_in[3];
    const float* b_ih   = (const float*)d_in[4];
    const float* b_hh   = (const float*)d_in[5];
    const float* head_w = (const float*)d_in[6];
    const float* head_b = (const float*)d_in[7];
    float* out = (float*)d_out;

    gru_seq_kernel<<<BB, NT, 0, stream>>>(x, len, W_ih, W_hh, b_ih, b_hh,
                                          head_w, head_b, out);
}

// Round 12
// 964.794 us; speedup vs baseline: 1.5467x; 1.0360x over previous
//
#include <hip/hip_runtime.h>

// GRU: B=256, T=2048, I=2, H=128. One workgroup (512 thr = 8 waves) per batch.
// R12 = R11 (best: 999 us) with the h-broadcast halved via fp16:
//   - h stored in LDS as fp16 (producer keeps fp32 h_reg for the recurrence;
//     only the broadcast copy is rounded). 4 ds_read_b128/thread/step vs 8.
//   - weights prescaled (-log2e r/z, 2log2e n) then packed to fp16: 48 VGPRs.
//   - dots via v_dot2_f32_f16 (2 MACs/instr, fp32 accumulate) -> same VALU
//     issue count as R11's pk_fma path.
// Structure frozen from R11: thread (q=tid&3, j=tid>>2) owns q-th 32-col
// slice of gate rows {j, 128+j, 256+j}; h double-buffered (40-HALF slice
// stride: per-instr banks = 16 distinct, quad-broadcast, conflict-free);
// xp/bhn folded into acc init (x1/4); non-volatile single-instr
// v_add_f32_dpp quad butterfly; unmasked exp2/rcp gates; x[t+1] prefetch;
// one barrier/step.
// Falsified (do not revisit): 16-col/8-lane-reduce family (R4/R6/R10,
// +500..950 cyc/step); VGPR-residency forcing (R3/R8, no-ops); occupancy
// swap 256thr/1wave (R7, neutral).

#define BB 256
#define TT 2048
#define HH 128
#define NT 512
#define HHALFS 160   // per buffer: 4 slices x 40 halfs (32 data + 8 pad)

typedef float v2f __attribute__((ext_vector_type(2)));
typedef _Float16 v2h __attribute__((ext_vector_type(2)));
typedef _Float16 v8h __attribute__((ext_vector_type(8)));

// x += dpp(x) in one v_add_f32_dpp; s_nop 1 covers the VALU->DPP hazard.
// Non-volatile: schedulable.
#define DPP_ADD_Q(x, QPSTR) do { float _d;                                   \
    asm("s_nop 1\n\t"                                                        \
        "v_add_f32_dpp %0, %1, %1 " QPSTR " row_mask:0xf bank_mask:0xf"      \
        : "=v"(_d) : "v"(x));                                                \
    (x) = _d; } while (0)

__global__ __launch_bounds__(NT, 2) void gru_seq_kernel(
    const float* __restrict__ x,        // [B, T, 2]
    const int*   __restrict__ lengths,  // [B]
    const float* __restrict__ W_ih,     // [384, 2]
    const float* __restrict__ W_hh,     // [384, 128]
    const float* __restrict__ b_ih,     // [384]
    const float* __restrict__ b_hh,     // [384]
    const float* __restrict__ head_w,   // [128]
    const float* __restrict__ head_b,   // [1]
    float* __restrict__ out)            // [B]
{
    __shared__ __align__(16) float x_lds[(TT + 1) * 2];      // 16 KB (+prefetch)
    __shared__ __align__(16) _Float16 h_lds[2][HHALFS];      // 640 B
    __shared__ float red[8];

    const int tid = threadIdx.x;
    const int q = tid & 3;          // 32-col slice
    const int j = tid >> 2;         // hidden index 0..127
    const int b = blockIdx.x;
    const int len = lengths[b];

    const float S_RZ = -1.4426950408889634f;   // -log2(e)
    const float S_N  =  2.8853900817779268f;   //  2*log2(e)

    // --- weights: prescale then pack to fp16 (16 v2h per gate = 48 regs) ---
    v2h wrh[16], wzh[16], wnh[16];
    {
        const float4* Wr = (const float4*)(W_hh + (size_t)j * HH + q * 32);
        const float4* Wz = (const float4*)(W_hh + (size_t)(HH + j) * HH + q * 32);
        const float4* Wn = (const float4*)(W_hh + (size_t)(2 * HH + j) * HH + q * 32);
        #pragma unroll
        for (int i = 0; i < 8; ++i) {
            const float4 a = Wr[i], c = Wz[i], d = Wn[i];
            wrh[2*i]   = (v2h){(_Float16)(S_RZ * a.x), (_Float16)(S_RZ * a.y)};
            wrh[2*i+1] = (v2h){(_Float16)(S_RZ * a.z), (_Float16)(S_RZ * a.w)};
            wzh[2*i]   = (v2h){(_Float16)(S_RZ * c.x), (_Float16)(S_RZ * c.y)};
            wzh[2*i+1] = (v2h){(_Float16)(S_RZ * c.z), (_Float16)(S_RZ * c.w)};
            wnh[2*i]   = (v2h){(_Float16)(S_N * d.x), (_Float16)(S_N * d.y)};
            wnh[2*i+1] = (v2h){(_Float16)(S_N * d.z), (_Float16)(S_N * d.w)};
        }
    }

    // --- all-lane init constants (x 1/4: quad butterfly sums 4 replicas) ---
    float wir0, wir1, br4, wiz0, wiz1, bz4, bhn4;
    {
        const float s4 = S_RZ * 0.25f;
        wir0 = s4 * W_ih[j * 2];        wir1 = s4 * W_ih[j * 2 + 1];
        br4  = s4 * (b_ih[j] + b_hh[j]);
        wiz0 = s4 * W_ih[(HH + j) * 2]; wiz1 = s4 * W_ih[(HH + j) * 2 + 1];
        bz4  = s4 * (b_ih[HH + j] + b_hh[HH + j]);
        bhn4 = (S_N * 0.25f) * b_hh[2 * HH + j];
    }
    // consumer-side n-gate input proj + head weight (valid on all lanes)
    const float win0 = S_N * W_ih[(2 * HH + j) * 2];
    const float win1 = S_N * W_ih[(2 * HH + j) * 2 + 1];
    const float bn   = S_N * b_ih[2 * HH + j];
    const float hw   = head_w[j];

    // --- stage x[b] into LDS (float4, coalesced) ---
    {
        const float4* xb4 = (const float4*)(x + (size_t)b * TT * 2);
        float4* xl4 = (float4*)x_lds;
        #pragma unroll
        for (int i = tid; i < TT * 2 / 4; i += NT) xl4[i] = xb4[i];
    }
    if (tid == 0) { x_lds[TT * 2] = 0.f; x_lds[TT * 2 + 1] = 0.f; }
    // zero both h buffers
    for (int i = tid; i < 2 * HHALFS; i += NT) ((_Float16*)h_lds)[i] = (_Float16)0.f;

    __syncthreads();

    float h_reg = 0.0f;   // fp32 h[j]; only q==0 lanes' value is live
    int buf = 0;
    const float2* x2 = (const float2*)x_lds;
    float2 xt = x2[0];

    for (int t = 0; t < len; ++t) {
        // h slice: 4 x ds_read_b128 of fp16 (quad-broadcast, conflict-free)
        const v8h* hb = (const v8h*)(&h_lds[buf][40 * q]);
        v8h hv[4];
        #pragma unroll
        for (int i = 0; i < 4; ++i) hv[i] = hb[i];

        const float2 xt_next = x2[t + 1];   // prefetch

        // split pairs
        v2h h2[16];
        #pragma unroll
        for (int i = 0; i < 4; ++i) {
            h2[4*i+0] = __builtin_shufflevector(hv[i], hv[i], 0, 1);
            h2[4*i+1] = __builtin_shufflevector(hv[i], hv[i], 2, 3);
            h2[4*i+2] = __builtin_shufflevector(hv[i], hv[i], 4, 5);
            h2[4*i+3] = __builtin_shufflevector(hv[i], hv[i], 6, 7);
        }

        // accumulator init: xp/4 (r,z) and bhn/4 (n) pre-folded
        float arA = fmaf(wir0, xt.x, fmaf(wir1, xt.y, br4)), arB = 0.f;
        float azA = fmaf(wiz0, xt.x, fmaf(wiz1, xt.y, bz4)), azB = 0.f;
        float anA = bhn4, anB = 0.f;

        #pragma unroll
        for (int i = 0; i < 8; ++i) {
            arA = __builtin_amdgcn_fdot2(wrh[i],     h2[i],     arA, false);
            arB = __builtin_amdgcn_fdot2(wrh[i + 8], h2[i + 8], arB, false);
            azA = __builtin_amdgcn_fdot2(wzh[i],     h2[i],     azA, false);
            azB = __builtin_amdgcn_fdot2(wzh[i + 8], h2[i + 8], azB, false);
            anA = __builtin_amdgcn_fdot2(wnh[i],     h2[i],     anA, false);
            anB = __builtin_amdgcn_fdot2(wnh[i + 8], h2[i + 8], anB, false);
        }
        float ar = arA + arB;
        float az = azA + azB;
        float an = anA + anB;

        // quad butterfly, acc-major interleave (non-volatile, schedulable)
        DPP_ADD_Q(ar, "quad_perm:[1,0,3,2]");
        DPP_ADD_Q(az, "quad_perm:[1,0,3,2]");
        DPP_ADD_Q(an, "quad_perm:[1,0,3,2]");
        DPP_ADD_Q(ar, "quad_perm:[2,3,0,1]");
        DPP_ADD_Q(az, "quad_perm:[2,3,0,1]");
        DPP_ADD_Q(an, "quad_perm:[2,3,0,1]");

        // gate chain unmasked (all quad lanes hold identical full sums);
        // ar/az/an already include xp and biases (prescaled)
        const float r = __builtin_amdgcn_rcpf(1.f + __builtin_amdgcn_exp2f(ar));
        const float z = __builtin_amdgcn_rcpf(1.f + __builtin_amdgcn_exp2f(az));
        const float xn = fmaf(win0, xt.x, fmaf(win1, xt.y, bn));
        const float u = __builtin_amdgcn_exp2f(fmaf(r, an, xn));
        const float n = fmaf(-2.f, __builtin_amdgcn_rcpf(1.f + u), 1.f);
        const float h_new = n + z * (h_reg - n);
        if (q == 0) {
            h_reg = h_new;
            h_lds[buf ^ 1][40 * (j >> 5) + (j & 31)] = (_Float16)h_new;
        }
        __syncthreads();
        buf ^= 1;
        xt = xt_next;
    }

    // --- head: out[b] = dot(h, head_w) + head_b ---
    float p = (q == 0) ? h_reg * hw : 0.0f;
    #pragma unroll
    for (int off = 32; off > 0; off >>= 1) p += __shfl_xor(p, off);
    const int wid = tid >> 6;
    if ((tid & 63) == 0) red[wid] = p;
    __syncthreads();
    if (tid == 0) {
        float s = red[0];
        #pragma unroll
        for (int i = 1; i < 8; ++i) s += red[i];
        out[b] = s + head_b[0];
    }
}

extern "C" void kernel_launch(void* const* d_in, const int* in_sizes, int n_in,
                              void* d_out, int out_size, void* d_ws, size_t ws_size,
                              hipStream_t stream) {
    const float* x      = (const float*)d_in[0];
    const int*   len    = (const int*)  d_in[1];
    const float* W_ih   = (const float*)d_in[2];
    const float* W_hh   = (const float*)d_in[3];
    const float* b_ih   = (const float*)d_in[4];
    const float* b_hh   = (const float*)d_in[5];
    const float* head_w = (const float*)d_in[6];
    const float* head_b = (const float*)d_in[7];
    float* out = (float*)d_out;

    gru_seq_kernel<<<BB, NT, 0, stream>>>(x, len, W_ih, W_hh, b_ih, b_hh,
                                          head_w, head_b, out);
}

// Round 13
// 921.976 us; speedup vs baseline: 1.6185x; 1.0464x over previous
//
#include <hip/hip_runtime.h>

// GRU: B=256, T=2048, I=2, H=128. One workgroup per batch element.
// R13 = R12 (best: 965 us) with rows-per-thread raised 3 -> 6.
//   Invariant: per-step h-broadcast bytes = 384*128*2 / rows_per_thread.
//   R12 (3 rows/thr, NT=512): 32 KB/step. R13: NT=256 (4 waves, 1/SIMD),
//   thread (q=tid&3, jp=tid>>2) owns gates {r,z,n} x units {jp, 64+jp},
//   cols [32q, 32q+32) -> 16 KB/step, same per-SIMD VALU issue
//   (96 dot2 x 1 wave == 48 x 2), same proven quad butterfly (12 DPP/thr),
//   4-wave barrier instead of 8.
//   Lane's consumer unit uSel = 64*(q&1) + jp fixed at setup (win/bn/hw/
//   write-addr are per-lane constants); only the acc pick needs 3 cndmask.
// Carried from R12: fp16 h in LDS (fp32 recurrence on producer), prescaled
// fp16 weights + v_dot2_f32_f16, xp/bhn folded into acc init (x1/4),
// non-volatile single-instr v_add_f32_dpp butterfly, exp2/rcp gates,
// x[t+1] prefetch, one barrier/step, 40-half slice stride (conflict-free).
// Falsified (do not revisit): 16-col/8-lane-reduce (R4/R6/R10); VGPR
// residency forcing (R3/R8); NT=256 at 3 rows/thr fp32 (R7, neutral).

#define BB 256
#define TT 2048
#define HH 128
#define NT 256
#define HHALFS 160   // per buffer: 4 slices x 40 halfs (32 data + 8 pad)

typedef _Float16 v2h __attribute__((ext_vector_type(2)));
typedef _Float16 v8h __attribute__((ext_vector_type(8)));

// x += dpp(x) in one v_add_f32_dpp; s_nop 1 covers the VALU->DPP hazard.
// Non-volatile: schedulable.
#define DPP_ADD_Q(x, QPSTR) do { float _d;                                   \
    asm("s_nop 1\n\t"                                                        \
        "v_add_f32_dpp %0, %1, %1 " QPSTR " row_mask:0xf bank_mask:0xf"      \
        : "=v"(_d) : "v"(x));                                                \
    (x) = _d; } while (0)

__global__ __launch_bounds__(NT, 1) void gru_seq_kernel(
    const float* __restrict__ x,        // [B, T, 2]
    const int*   __restrict__ lengths,  // [B]
    const float* __restrict__ W_ih,     // [384, 2]
    const float* __restrict__ W_hh,     // [384, 128]
    const float* __restrict__ b_ih,     // [384]
    const float* __restrict__ b_hh,     // [384]
    const float* __restrict__ head_w,   // [128]
    const float* __restrict__ head_b,   // [1]
    float* __restrict__ out)            // [B]
{
    __shared__ __align__(16) float x_lds[(TT + 1) * 2];      // 16 KB (+prefetch)
    __shared__ __align__(16) _Float16 h_lds[2][HHALFS];      // 640 B
    __shared__ float red[HH];

    const int tid = threadIdx.x;
    const int q  = tid & 3;          // 32-col slice
    const int jp = tid >> 2;         // unit-pair index 0..63
    const int b  = blockIdx.x;
    const int len = lengths[b];

    const float S_RZ = -1.4426950408889634f;   // -log2(e)
    const float S_N  =  2.8853900817779268f;   //  2*log2(e)

    // --- weights: 6 rows (g x p) x 32-col slice q, prescaled fp16 ---
    // wv[g*2+p][i], i in [0,16): v2h pairs of row (g*128 + 64p + jp)
    v2h wv[6][16];
    #pragma unroll
    for (int g = 0; g < 3; ++g) {
        const float s = (g == 2) ? S_N : S_RZ;
        #pragma unroll
        for (int p = 0; p < 2; ++p) {
            const float4* Wp = (const float4*)(W_hh + (size_t)(g * HH + 64 * p + jp) * HH + 32 * q);
            #pragma unroll
            for (int i = 0; i < 8; ++i) {
                const float4 w4 = Wp[i];
                wv[g * 2 + p][2 * i]     = (v2h){(_Float16)(s * w4.x), (_Float16)(s * w4.y)};
                wv[g * 2 + p][2 * i + 1] = (v2h){(_Float16)(s * w4.z), (_Float16)(s * w4.w)};
            }
        }
    }

    // --- all-lane init constants (x 1/4: quad butterfly sums 4 replicas) ---
    float wir0[2], wir1[2], br4[2], wiz0[2], wiz1[2], bz4[2], bhn4[2];
    #pragma unroll
    for (int p = 0; p < 2; ++p) {
        const int u = 64 * p + jp;
        const float s4 = S_RZ * 0.25f;
        wir0[p] = s4 * W_ih[u * 2];        wir1[p] = s4 * W_ih[u * 2 + 1];
        br4[p]  = s4 * (b_ih[u] + b_hh[u]);
        wiz0[p] = s4 * W_ih[(HH + u) * 2]; wiz1[p] = s4 * W_ih[(HH + u) * 2 + 1];
        bz4[p]  = s4 * (b_ih[HH + u] + b_hh[HH + u]);
        bhn4[p] = (S_N * 0.25f) * b_hh[2 * HH + u];
    }

    // --- per-lane consumer unit: uSel = 64*(q&1) + jp ---
    const int pSel = q & 1;
    const int uSel = 64 * pSel + jp;
    const float win0 = S_N * W_ih[(2 * HH + uSel) * 2];
    const float win1 = S_N * W_ih[(2 * HH + uSel) * 2 + 1];
    const float bn   = S_N * b_ih[2 * HH + uSel];
    const float hw   = head_w[uSel];

    // --- stage x[b] into LDS (float4, coalesced) ---
    {
        const float4* xb4 = (const float4*)(x + (size_t)b * TT * 2);
        float4* xl4 = (float4*)x_lds;
        #pragma unroll
        for (int i = tid; i < TT * 2 / 4; i += NT) xl4[i] = xb4[i];
    }
    if (tid == 0) { x_lds[TT * 2] = 0.f; x_lds[TT * 2 + 1] = 0.f; }
    for (int i = tid; i < 2 * HHALFS; i += NT) ((_Float16*)h_lds)[i] = (_Float16)0.f;

    __syncthreads();

    float h_reg = 0.0f;   // fp32 h[uSel]; live on lanes q<2
    int buf = 0;
    const float2* x2 = (const float2*)x_lds;
    float2 xt = x2[0];

    for (int t = 0; t < len; ++t) {
        // h slice q: 4 x ds_read_b128 of fp16 (quad-broadcast, conflict-free)
        const v8h* hb = (const v8h*)(&h_lds[buf][40 * q]);
        v8h hv[4];
        #pragma unroll
        for (int i = 0; i < 4; ++i) hv[i] = hb[i];

        const float2 xt_next = x2[t + 1];   // prefetch

        v2h h2[16];
        #pragma unroll
        for (int i = 0; i < 4; ++i) {
            h2[4*i+0] = __builtin_shufflevector(hv[i], hv[i], 0, 1);
            h2[4*i+1] = __builtin_shufflevector(hv[i], hv[i], 2, 3);
            h2[4*i+2] = __builtin_shufflevector(hv[i], hv[i], 4, 5);
            h2[4*i+3] = __builtin_shufflevector(hv[i], hv[i], 6, 7);
        }

        // acc inits: xp/4 (r,z) and bhn/4 (n), per unit p
        float aR[2], aZ[2], aN[2];
        #pragma unroll
        for (int p = 0; p < 2; ++p) {
            aR[p] = fmaf(wir0[p], xt.x, fmaf(wir1[p], xt.y, br4[p]));
            aZ[p] = fmaf(wiz0[p], xt.x, fmaf(wiz1[p], xt.y, bz4[p]));
            aN[p] = bhn4[p];
        }

        // 6 dots x 16 dot2 (fp32 accumulate)
        #pragma unroll
        for (int i = 0; i < 16; ++i) {
            aR[0] = __builtin_amdgcn_fdot2(wv[0][i], h2[i], aR[0], false);
            aR[1] = __builtin_amdgcn_fdot2(wv[1][i], h2[i], aR[1], false);
            aZ[0] = __builtin_amdgcn_fdot2(wv[2][i], h2[i], aZ[0], false);
            aZ[1] = __builtin_amdgcn_fdot2(wv[3][i], h2[i], aZ[1], false);
            aN[0] = __builtin_amdgcn_fdot2(wv[4][i], h2[i], aN[0], false);
            aN[1] = __builtin_amdgcn_fdot2(wv[5][i], h2[i], aN[1], false);
        }

        // quad butterfly, acc-major interleave (non-volatile, schedulable)
        DPP_ADD_Q(aR[0], "quad_perm:[1,0,3,2]");
        DPP_ADD_Q(aR[1], "quad_perm:[1,0,3,2]");
        DPP_ADD_Q(aZ[0], "quad_perm:[1,0,3,2]");
        DPP_ADD_Q(aZ[1], "quad_perm:[1,0,3,2]");
        DPP_ADD_Q(aN[0], "quad_perm:[1,0,3,2]");
        DPP_ADD_Q(aN[1], "quad_perm:[1,0,3,2]");
        DPP_ADD_Q(aR[0], "quad_perm:[2,3,0,1]");
        DPP_ADD_Q(aR[1], "quad_perm:[2,3,0,1]");
        DPP_ADD_Q(aZ[0], "quad_perm:[2,3,0,1]");
        DPP_ADD_Q(aZ[1], "quad_perm:[2,3,0,1]");
        DPP_ADD_Q(aN[0], "quad_perm:[2,3,0,1]");
        DPP_ADD_Q(aN[1], "quad_perm:[2,3,0,1]");

        // pick this lane's unit (pSel = q&1); lanes q>=2 compute a dup
        const float ar = pSel ? aR[1] : aR[0];
        const float az = pSel ? aZ[1] : aZ[0];
        const float an = pSel ? aN[1] : aN[0];

        // gate chain (unmasked; ar/az/an include xp and biases, prescaled)
        const float r = __builtin_amdgcn_rcpf(1.f + __builtin_amdgcn_exp2f(ar));
        const float z = __builtin_amdgcn_rcpf(1.f + __builtin_amdgcn_exp2f(az));
        const float xn = fmaf(win0, xt.x, fmaf(win1, xt.y, bn));
        const float u = __builtin_amdgcn_exp2f(fmaf(r, an, xn));
        const float n = fmaf(-2.f, __builtin_amdgcn_rcpf(1.f + u), 1.f);
        const float h_new = n + z * (h_reg - n);
        if (q < 2) {
            h_reg = h_new;
            h_lds[buf ^ 1][40 * (uSel >> 5) + (uSel & 31)] = (_Float16)h_new;
        }
        __syncthreads();
        buf ^= 1;
        xt = xt_next;
    }

    // --- head: out[b] = dot(h, head_w) + head_b ---
    if (q < 2) red[uSel] = h_reg * hw;
    __syncthreads();
    if (tid < 64) {
        float v = red[tid] + red[tid + 64];
        #pragma unroll
        for (int off = 32; off > 0; off >>= 1) v += __shfl_xor(v, off, 64);
        if (tid == 0) out[b] = v + head_b[0];
    }
}

extern "C" void kernel_launch(void* const* d_in, const int* in_sizes, int n_in,
                              void* d_out, int out_size, void* d_ws, size_t ws_size,
                              hipStream_t stream) {
    const float* x      = (const float*)d_in[0];
    const int*   len    = (const int*)  d_in[1];
    const float* W_ih   = (const float*)d_in[2];
    const float* W_hh   = (const float*)d_in[3];
    const float* b_ih   = (const float*)d_in[4];
    const float* b_hh   = (const float*)d_in[5];
    const float* head_w = (const float*)d_in[6];
    const float* head_b = (const float*)d_in[7];
    float* out = (float*)d_out;

    gru_seq_kernel<<<BB, NT, 0, stream>>>(x, len, W_ih, W_hh, b_ih, b_hh,
                                          head_w, head_b, out);
}